// Round 2
// baseline (723.968 us; speedup 1.0000x reference)
//
#include <hip/hip_runtime.h>
#include <cmath>

#define TW 64          // tile width  (output cols)
#define TH 32          // tile height (output rows)
#define SP 84          // LDS row stride in floats (80 stored cols + 4 pad)
#define NCG 20         // col groups (80/4)
#define NRG 8          // row groups (32/4)

struct Coeffs { float k[11]; };

__device__ __forceinline__ float4 ld4s(const float* __restrict__ p, int r, int c, int H, int W) {
    float4 v = make_float4(0.f, 0.f, 0.f, 0.f);
    if (r >= 0 && r < H) {
        const float* row = p + (size_t)r * W;
        if (c >= 0 && c + 3 < W) {
            v = *reinterpret_cast<const float4*>(row + c);
        } else {
            if (c + 0 >= 0 && c + 0 < W) v.x = row[c + 0];
            if (c + 1 >= 0 && c + 1 < W) v.y = row[c + 1];
            if (c + 2 >= 0 && c + 2 < W) v.z = row[c + 2];
            if (c + 3 >= 0 && c + 3 < W) v.w = row[c + 3];
        }
    }
    return v;
}

__device__ __forceinline__ void vrow(const Coeffs& cf, float4 a, float4 b, int ri,
                                     float (&acc)[5][4][4],
                                     float (&kp1)[4][4], float (&kp2)[4][4]) {
    float av[4] = {a.x, a.y, a.z, a.w};
    float bv[4] = {b.x, b.y, b.z, b.w};
    float paa[4], pbb[4], pab[4];
    #pragma unroll
    for (int c = 0; c < 4; ++c) {
        paa[c] = av[c] * av[c];
        pbb[c] = bv[c] * bv[c];
        pab[c] = av[c] * bv[c];
    }
    if (ri >= 5 && ri <= 8) {           // ri compile-time after full unroll
        #pragma unroll
        for (int c = 0; c < 4; ++c) { kp1[ri - 5][c] = av[c]; kp2[ri - 5][c] = bv[c]; }
    }
    #pragma unroll
    for (int i = 0; i < 4; ++i) {
        int t = ri - i;                 // compile-time: static k[] index, no scratch
        if (t >= 0 && t <= 10) {
            float kk = cf.k[t];
            #pragma unroll
            for (int c = 0; c < 4; ++c) {
                acc[0][i][c] += kk * av[c];
                acc[1][i][c] += kk * bv[c];
                acc[2][i][c] += kk * paa[c];
                acc[3][i][c] += kk * pbb[c];
                acc[4][i][c] += kk * pab[c];
            }
        }
    }
}

__global__ __launch_bounds__(256)
void ssim_level_kernel(const float* __restrict__ i1, const float* __restrict__ i2,
                       float* __restrict__ o1, float* __restrict__ o2,
                       int H, int W, int tilesX,
                       double* __restrict__ accum, Coeffs cf)
{
    __shared__ __align__(16) float varr[5][TH][SP];   // 53.76 KB -> 3 blocks/CU
    __shared__ double red[2][4];

    const int tid = threadIdx.x;
    const int bc  = blockIdx.y;
    const int tileY = blockIdx.x / tilesX;
    const int tileX = blockIdx.x - tileY * tilesX;
    const int r0 = tileY * TH;
    const int c0 = tileX * TW;
    const float* p1 = i1 + (size_t)bc * H * W;
    const float* p2 = i2 + (size_t)bc * H * W;

    // ---------------- V phase: vertical 11-tap of 5 streams, global -> regs -> LDS ----
    if (tid < NCG * NRG) {
        const int cg = tid % NCG;
        const int rg = tid / NCG;
        const int sc = 4 * cg;              // stored col
        const int gc = c0 - 8 + sc;         // global col of this 4-col group
        const int rbase = r0 + rg * 4 - 5;  // first input row

        float acc[5][4][4] = {};            // [stream][out_row][col]
        float kp1[4][4], kp2[4][4];         // raw rows rg*4..rg*4+3 kept for avg-pool

        const bool safe = (rbase >= 0) && (rbase + 13 < H) && (gc >= 0) && (gc + 3 < W);
        if (safe) {
            const float* a0 = p1 + (size_t)rbase * W + gc;
            const float* b0 = p2 + (size_t)rbase * W + gc;
            #pragma unroll
            for (int ri = 0; ri < 14; ++ri) {
                float4 a = *reinterpret_cast<const float4*>(a0 + (size_t)ri * W);
                float4 b = *reinterpret_cast<const float4*>(b0 + (size_t)ri * W);
                vrow(cf, a, b, ri, acc, kp1, kp2);
            }
        } else {
            #pragma unroll
            for (int ri = 0; ri < 14; ++ri) {
                float4 a = ld4s(p1, rbase + ri, gc, H, W);
                float4 b = ld4s(p2, rbase + ri, gc, H, W);
                vrow(cf, a, b, ri, acc, kp1, kp2);
            }
        }

        #pragma unroll
        for (int ar = 0; ar < 5; ++ar) {
            #pragma unroll
            for (int i = 0; i < 4; ++i) {
                *reinterpret_cast<float4*>(&varr[ar][rg * 4 + i][sc]) =
                    make_float4(acc[ar][i][0], acc[ar][i][1], acc[ar][i][2], acc[ar][i][3]);
            }
        }

        // fused 2x2 avg-pool for the next level (from registers)
        if (o1 != nullptr && cg >= 2 && cg < 18) {
            const int W2 = W >> 1;
            float2 a_r0, a_r1, b_r0, b_r1;
            a_r0.x = 0.25f * (kp1[0][0] + kp1[0][1] + kp1[1][0] + kp1[1][1]);
            a_r0.y = 0.25f * (kp1[0][2] + kp1[0][3] + kp1[1][2] + kp1[1][3]);
            a_r1.x = 0.25f * (kp1[2][0] + kp1[2][1] + kp1[3][0] + kp1[3][1]);
            a_r1.y = 0.25f * (kp1[2][2] + kp1[2][3] + kp1[3][2] + kp1[3][3]);
            b_r0.x = 0.25f * (kp2[0][0] + kp2[0][1] + kp2[1][0] + kp2[1][1]);
            b_r0.y = 0.25f * (kp2[0][2] + kp2[0][3] + kp2[1][2] + kp2[1][3]);
            b_r1.x = 0.25f * (kp2[2][0] + kp2[2][1] + kp2[3][0] + kp2[3][1]);
            b_r1.y = 0.25f * (kp2[2][2] + kp2[2][3] + kp2[3][2] + kp2[3][3]);
            const size_t base = (size_t)bc * (size_t)(H >> 1) * W2
                              + (size_t)((r0 + rg * 4) >> 1) * W2 + (gc >> 1);
            *reinterpret_cast<float2*>(o1 + base)      = a_r0;
            *reinterpret_cast<float2*>(o1 + base + W2) = a_r1;
            *reinterpret_cast<float2*>(o2 + base)      = b_r0;
            *reinterpret_cast<float2*>(o2 + base + W2) = b_r1;
        }
    }
    __syncthreads();

    // ---------------- H phase: horizontal 11-tap of the 5 arrays + SSIM ---------------
    const int row = tid >> 3;           // 0..31
    const int cl  = (tid & 7) << 3;     // local output col 0,8,...,56

    float conv[5][8];
    #pragma unroll
    for (int ar = 0; ar < 5; ++ar) {
        float w[24];
        #pragma unroll
        for (int g = 0; g < 6; ++g) {
            float4 v = *reinterpret_cast<const float4*>(&varr[ar][row][cl + 4 * g]);
            w[4*g+0] = v.x; w[4*g+1] = v.y; w[4*g+2] = v.z; w[4*g+3] = v.w;
        }
        #pragma unroll
        for (int j = 0; j < 8; ++j) {
            float s = 0.f;
            #pragma unroll
            for (int t = 0; t < 11; ++t) s += cf.k[t] * w[j + 3 + t];
            conv[ar][j] = s;
        }
    }

    const float C1 = 1e-4f, C2 = 9e-4f;
    float ssim_acc = 0.f, cs_acc = 0.f;
    #pragma unroll
    for (int j = 0; j < 8; ++j) {
        if (c0 + cl + j < W) {          // col mask (only level 4 has W < TW)
            float mu1 = conv[0][j], mu2 = conv[1][j];
            float m11 = conv[2][j], m22 = conv[3][j], m12 = conv[4][j];
            float mu1s = mu1 * mu1, mu2s = mu2 * mu2, mu12 = mu1 * mu2;
            float v1 = 2.f * (m12 - mu12) + C2;
            float v2 = (m11 - mu1s) + (m22 - mu2s) + C2;
            cs_acc   += v1 / v2;
            ssim_acc += ((2.f * mu12 + C1) * v1) / ((mu1s + mu2s + C1) * v2);
        }
    }

    // ---------------- block reduction + spread-slot atomics ---------------------------
    #pragma unroll
    for (int off = 32; off > 0; off >>= 1) {
        ssim_acc += __shfl_down(ssim_acc, off);
        cs_acc   += __shfl_down(cs_acc, off);
    }
    const int wave = tid >> 6, lane = tid & 63;
    if (lane == 0) { red[0][wave] = (double)ssim_acc; red[1][wave] = (double)cs_acc; }
    __syncthreads();
    if (tid == 0) {
        double s = red[0][0] + red[0][1] + red[0][2] + red[0][3];
        double c = red[1][0] + red[1][1] + red[1][2] + red[1][3];
        int slot = (blockIdx.x + blockIdx.y) & 63;
        atomicAdd(&accum[slot], s);
        atomicAdd(&accum[64 + slot], c);
    }
}

__global__ __launch_bounds__(64)
void finalize_kernel(const double* __restrict__ accum,  // [5][2][64]
                     float* __restrict__ out, int BC)
{
    __shared__ double sums[5][2];
    int tid = threadIdx.x;
    for (int lvl = 0; lvl < 5; ++lvl) {
        for (int m = 0; m < 2; ++m) {
            double v = accum[(lvl * 2 + m) * 64 + tid];
            for (int off = 32; off > 0; off >>= 1) v += __shfl_down(v, off);
            if (tid == 0) sums[lvl][m] = v;
        }
    }
    __syncthreads();
    if (tid == 0) {
        const double w[5] = {0.0448, 0.2856, 0.3001, 0.2363, 0.1333};
        double prod = 1.0;
        for (int lvl = 0; lvl < 5; ++lvl) {
            int hw = (512 >> lvl);
            double cnt = (double)BC * (double)hw * (double)hw;
            double mssim = sums[lvl][0] / cnt;
            double mcs   = sums[lvl][1] / cnt;
            if (lvl < 4) {
                prod *= pow(mcs, w[lvl]);
            } else {
                double p2 = pow(mssim, w[4]);
                prod *= p2 * p2 * p2 * p2;   // pow2[-1] broadcast across the 4 products
            }
        }
        out[0] = (float)(1.0 - prod);
    }
}

extern "C" void kernel_launch(void* const* d_in, const int* in_sizes, int n_in,
                              void* d_out, int out_size, void* d_ws, size_t ws_size,
                              hipStream_t stream) {
    const float* img1 = (const float*)d_in[0];
    const float* img2 = (const float*)d_in[1];
    float* out = (float*)d_out;
    char* ws = (char*)d_ws;

    const int BC = in_sizes[0] / (512 * 512);   // 96

    // ws layout: [0,5120): double accum[5][2][64]; pyramid buffers from 8192
    double* accum = (double*)ws;
    size_t off = 8192;
    float* lvl1[5] = {nullptr, nullptr, nullptr, nullptr, nullptr};
    float* lvl2[5] = {nullptr, nullptr, nullptr, nullptr, nullptr};
    for (int l = 1; l < 5; ++l) {
        size_t hw = (size_t)(512 >> l) * (512 >> l);
        lvl1[l] = (float*)(ws + off); off += (size_t)BC * hw * sizeof(float);
        lvl2[l] = (float*)(ws + off); off += (size_t)BC * hw * sizeof(float);
    }

    hipMemsetAsync(accum, 0, 5 * 2 * 64 * sizeof(double), stream);

    // Gaussian window, faithful to the reference's POSITIVE exponent bug
    Coeffs cf;
    {
        double kd[11], sum = 0.0;
        for (int i = 0; i < 11; ++i) { kd[i] = exp(((double)((i-5)*(i-5))) / 4.5); sum += kd[i]; }
        for (int i = 0; i < 11; ++i) cf.k[i] = (float)(kd[i] / sum);
    }

    const float* cur1 = img1;
    const float* cur2 = img2;
    for (int lvl = 0; lvl < 5; ++lvl) {
        int H = 512 >> lvl, W = H;
        int tilesX = (W + TW - 1) / TW;
        int tilesY = (H + TH - 1) / TH;
        dim3 grid(tilesX * tilesY, BC);
        float* n1 = (lvl < 4) ? lvl1[lvl + 1] : nullptr;
        float* n2 = (lvl < 4) ? lvl2[lvl + 1] : nullptr;
        ssim_level_kernel<<<grid, 256, 0, stream>>>(cur1, cur2, n1, n2, H, W, tilesX,
                                                    accum + lvl * 128, cf);
        cur1 = n1; cur2 = n2;
    }

    finalize_kernel<<<1, 64, 0, stream>>>(accum, out, BC);
}

// Round 3
// 272.164 us; speedup vs baseline: 2.6600x; 2.6600x over previous
//
#include <hip/hip_runtime.h>
#include <cmath>

#define TW 32
#define TH 32
#define SP 33            // LDS row stride (32 + 1 pad) -> conflict-free V reads
#define HR 42            // TH + 10 halo rows

struct Coeffs { float k[11]; };

__device__ __forceinline__ float4 ld4s(const float* __restrict__ p, int r, int c, int H, int W) {
    float4 v = make_float4(0.f, 0.f, 0.f, 0.f);
    if (r >= 0 && r < H) {
        const float* row = p + (size_t)r * W;
        if (c >= 0 && c + 3 < W) {
            v = *reinterpret_cast<const float4*>(row + c);
        } else {
            if (c + 0 >= 0 && c + 0 < W) v.x = row[c + 0];
            if (c + 1 >= 0 && c + 1 < W) v.y = row[c + 1];
            if (c + 2 >= 0 && c + 2 < W) v.z = row[c + 2];
            if (c + 3 >= 0 && c + 3 < W) v.w = row[c + 3];
        }
    }
    return v;
}

__global__ __launch_bounds__(256)
void ssim_level_kernel(const float* __restrict__ i1, const float* __restrict__ i2,
                       float* __restrict__ o1, float* __restrict__ o2,
                       int H, int W, int tilesX,
                       double* __restrict__ accum, Coeffs cf)
{
    __shared__ __align__(16) float varr[5][HR][SP];   // 27.7 KB
    __shared__ __align__(16) float phl[2][16][16];    // 2 KB pooled pair-sums (odd rows)
    __shared__ double red[2][4];

    const int tid = threadIdx.x;
    const int bc  = blockIdx.y;
    const int tileY = blockIdx.x / tilesX;
    const int tileX = blockIdx.x - tileY * tilesX;
    const int r0 = tileY * TH;
    const int c0 = tileX * TW;
    const float* p1 = i1 + (size_t)bc * H * W;
    const float* p2 = i2 + (size_t)bc * H * W;

    // ======== H phase: 11-tap horizontal conv of 5 streams, global regs -> LDS ======
    // 168 threads: row_rel 0..41 (image row r0+row_rel-5), j = 8-col group 0..3
    const int row_rel = tid >> 2;
    const int j  = tid & 3;
    const int cl = 8 * j;
    float hpA[4], hpB[4];            // pooling pair-sums, live across the barrier
    bool pool_thread = false;

    if (tid < HR * 4) {
        const int gr  = r0 + row_rel - 5;
        const int gcb = c0 + cl - 8;

        float a[24], b[24];
        if (gr >= 0 && gr < H && gcb >= 0 && gcb + 24 <= W) {
            const float* pa = p1 + (size_t)gr * W + gcb;
            const float* pb = p2 + (size_t)gr * W + gcb;
            #pragma unroll
            for (int g = 0; g < 6; ++g) {
                float4 va = *reinterpret_cast<const float4*>(pa + 4 * g);
                float4 vb = *reinterpret_cast<const float4*>(pb + 4 * g);
                a[4*g+0]=va.x; a[4*g+1]=va.y; a[4*g+2]=va.z; a[4*g+3]=va.w;
                b[4*g+0]=vb.x; b[4*g+1]=vb.y; b[4*g+2]=vb.z; b[4*g+3]=vb.w;
            }
        } else {
            #pragma unroll
            for (int g = 0; g < 6; ++g) {
                float4 va = ld4s(p1, gr, gcb + 4 * g, H, W);
                float4 vb = ld4s(p2, gr, gcb + 4 * g, H, W);
                a[4*g+0]=va.x; a[4*g+1]=va.y; a[4*g+2]=va.z; a[4*g+3]=va.w;
                b[4*g+0]=vb.x; b[4*g+1]=vb.y; b[4*g+2]=vb.z; b[4*g+3]=vb.w;
            }
        }

        // scatter-form conv: acc[s][out] = sum_t k[t] * val[out+3+t]
        float acc[5][8] = {};
        #pragma unroll
        for (int i = 0; i < 24; ++i) {
            float av = a[i], bv = b[i];
            float pa2 = av * av, pb2 = bv * bv, pab = av * bv;
            #pragma unroll
            for (int jo = 0; jo < 8; ++jo) {
                const int t = i - 3 - jo;
                if (t >= 0 && t <= 10) {
                    const float kk = cf.k[t];
                    acc[0][jo] += kk * av;  acc[1][jo] += kk * bv;
                    acc[2][jo] += kk * pa2; acc[3][jo] += kk * pb2;
                    acc[4][jo] += kk * pab;
                }
            }
        }
        #pragma unroll
        for (int s = 0; s < 5; ++s) {
            *reinterpret_cast<float4*>(&varr[s][row_rel][cl]) =
                make_float4(acc[s][0], acc[s][1], acc[s][2], acc[s][3]);
            *reinterpret_cast<float4*>(&varr[s][row_rel][cl + 4]) =
                make_float4(acc[s][4], acc[s][5], acc[s][6], acc[s][7]);
        }

        // pooling pair-sums from raw regs (a[8..15] = cols c0+cl .. +7)
        if (o1 != nullptr && row_rel >= 5 && row_rel <= 36) {
            #pragma unroll
            for (int p = 0; p < 4; ++p) {
                hpA[p] = a[8 + 2*p] + a[9 + 2*p];
                hpB[p] = b[8 + 2*p] + b[9 + 2*p];
            }
            if (row_rel & 1) {   // first row of a 2x2 pair (raw row even)
                const int i = (row_rel - 5) >> 1;
                *reinterpret_cast<float4*>(&phl[0][i][4*j]) = make_float4(hpA[0],hpA[1],hpA[2],hpA[3]);
                *reinterpret_cast<float4*>(&phl[1][i][4*j]) = make_float4(hpB[0],hpB[1],hpB[2],hpB[3]);
            } else if (row_rel >= 6) {
                pool_thread = true;  // second row: combines + writes after the barrier
            }
        }
    }
    __syncthreads();

    // ---- pooled 2x2 output for next level ----
    if (pool_thread) {
        const int i = (row_rel - 6) >> 1;
        const int W2 = W >> 1;
        float4 qa = *reinterpret_cast<const float4*>(&phl[0][i][4*j]);
        float4 qb = *reinterpret_cast<const float4*>(&phl[1][i][4*j]);
        qa.x = 0.25f*(qa.x + hpA[0]); qa.y = 0.25f*(qa.y + hpA[1]);
        qa.z = 0.25f*(qa.z + hpA[2]); qa.w = 0.25f*(qa.w + hpA[3]);
        qb.x = 0.25f*(qb.x + hpB[0]); qb.y = 0.25f*(qb.y + hpB[1]);
        qb.z = 0.25f*(qb.z + hpB[2]); qb.w = 0.25f*(qb.w + hpB[3]);
        const size_t base = (size_t)bc * (size_t)(H >> 1) * W2
                          + (size_t)(r0/2 + i) * W2 + (c0/2 + 4*j);
        *reinterpret_cast<float4*>(o1 + base) = qa;
        *reinterpret_cast<float4*>(o2 + base) = qb;
    }

    // ======== V phase: 11-tap vertical conv from LDS + SSIM ========================
    const int col = tid & 31;
    const int rg  = tid >> 5;           // 8 groups x 4 rows

    float acc[5][4] = {};
    #pragma unroll
    for (int t = 0; t < 14; ++t) {
        const int m = rg * 4 + t;
        #pragma unroll
        for (int s = 0; s < 5; ++s) {
            const float val = varr[s][m][col];
            #pragma unroll
            for (int i = 0; i < 4; ++i) {
                const int tap = t - i;
                if (tap >= 0 && tap <= 10) acc[s][i] += cf.k[tap] * val;
            }
        }
    }

    const float C1 = 1e-4f, C2 = 9e-4f;
    float ssim_acc = 0.f, cs_acc = 0.f;
    #pragma unroll
    for (int i = 0; i < 4; ++i) {
        const float mu1 = acc[0][i], mu2 = acc[1][i];
        const float m11 = acc[2][i], m22 = acc[3][i], m12 = acc[4][i];
        const float mu1s = mu1 * mu1, mu2s = mu2 * mu2, mu12 = mu1 * mu2;
        const float v1 = 2.f * (m12 - mu12) + C2;
        const float v2 = (m11 - mu1s) + (m22 - mu2s) + C2;
        cs_acc   += v1 / v2;
        ssim_acc += ((2.f * mu12 + C1) * v1) / ((mu1s + mu2s + C1) * v2);
    }

    // ======== reduction ============================================================
    double sd = (double)ssim_acc, cd = (double)cs_acc;
    #pragma unroll
    for (int off = 32; off > 0; off >>= 1) {
        sd += __shfl_down(sd, off);
        cd += __shfl_down(cd, off);
    }
    const int wave = tid >> 6, lane = tid & 63;
    if (lane == 0) { red[0][wave] = sd; red[1][wave] = cd; }
    __syncthreads();
    if (tid == 0) {
        double s = red[0][0] + red[0][1] + red[0][2] + red[0][3];
        double c = red[1][0] + red[1][1] + red[1][2] + red[1][3];
        int slot = (blockIdx.x + blockIdx.y) & 63;
        atomicAdd(&accum[slot], s);
        atomicAdd(&accum[64 + slot], c);
    }
}

__global__ __launch_bounds__(64)
void finalize_kernel(const double* __restrict__ accum,  // [5][2][64]
                     float* __restrict__ out, int BC)
{
    __shared__ double sums[5][2];
    int tid = threadIdx.x;
    for (int lvl = 0; lvl < 5; ++lvl) {
        for (int m = 0; m < 2; ++m) {
            double v = accum[(lvl * 2 + m) * 64 + tid];
            for (int off = 32; off > 0; off >>= 1) v += __shfl_down(v, off);
            if (tid == 0) sums[lvl][m] = v;
        }
    }
    __syncthreads();
    if (tid == 0) {
        const double w[5] = {0.0448, 0.2856, 0.3001, 0.2363, 0.1333};
        double prod = 1.0;
        for (int lvl = 0; lvl < 5; ++lvl) {
            int hw = (512 >> lvl);
            double cnt = (double)BC * (double)hw * (double)hw;
            double mssim = sums[lvl][0] / cnt;
            double mcs   = sums[lvl][1] / cnt;
            if (lvl < 4) {
                prod *= pow(mcs, w[lvl]);
            } else {
                double p2 = pow(mssim, w[4]);
                prod *= p2 * p2 * p2 * p2;   // pow2[-1] broadcast across the 4 products
            }
        }
        out[0] = (float)(1.0 - prod);
    }
}

extern "C" void kernel_launch(void* const* d_in, const int* in_sizes, int n_in,
                              void* d_out, int out_size, void* d_ws, size_t ws_size,
                              hipStream_t stream) {
    const float* img1 = (const float*)d_in[0];
    const float* img2 = (const float*)d_in[1];
    float* out = (float*)d_out;
    char* ws = (char*)d_ws;

    const int BC = in_sizes[0] / (512 * 512);   // 96

    double* accum = (double*)ws;
    size_t off = 8192;
    float* lvl1[5] = {nullptr, nullptr, nullptr, nullptr, nullptr};
    float* lvl2[5] = {nullptr, nullptr, nullptr, nullptr, nullptr};
    for (int l = 1; l < 5; ++l) {
        size_t hw = (size_t)(512 >> l) * (512 >> l);
        lvl1[l] = (float*)(ws + off); off += (size_t)BC * hw * sizeof(float);
        lvl2[l] = (float*)(ws + off); off += (size_t)BC * hw * sizeof(float);
    }

    hipMemsetAsync(accum, 0, 5 * 2 * 64 * sizeof(double), stream);

    // Gaussian window, faithful to the reference's POSITIVE exponent bug
    Coeffs cf;
    {
        double kd[11], sum = 0.0;
        for (int i = 0; i < 11; ++i) { kd[i] = exp(((double)((i-5)*(i-5))) / 4.5); sum += kd[i]; }
        for (int i = 0; i < 11; ++i) cf.k[i] = (float)(kd[i] / sum);
    }

    const float* cur1 = img1;
    const float* cur2 = img2;
    for (int lvl = 0; lvl < 5; ++lvl) {
        int H = 512 >> lvl, W = H;
        int tilesX = W / TW;
        int tilesY = H / TH;
        dim3 grid(tilesX * tilesY, BC);
        float* n1 = (lvl < 4) ? lvl1[lvl + 1] : nullptr;
        float* n2 = (lvl < 4) ? lvl2[lvl + 1] : nullptr;
        ssim_level_kernel<<<grid, 256, 0, stream>>>(cur1, cur2, n1, n2, H, W, tilesX,
                                                    accum + lvl * 128, cf);
        cur1 = n1; cur2 = n2;
    }

    finalize_kernel<<<1, 64, 0, stream>>>(accum, out, BC);
}